// Round 1
// 549.271 us; speedup vs baseline: 1.0596x; 1.0596x over previous
//
#include <hip/hip_runtime.h>
#include <stdint.h>
#include <stddef.h>

// Problem constants
#define DDIM 4096
#define MROWS 8192          // 4 * 2048
#define RANK 8

typedef __attribute__((ext_vector_type(8))) short bf16x8;    // 8 bf16 = 4 VGPRs
typedef __attribute__((ext_vector_type(16))) float f32x16;
typedef __attribute__((ext_vector_type(8))) unsigned short u16x8;

// RNE float -> bf16 bits
__device__ __forceinline__ unsigned short f2bf(float f) {
  union { float f; unsigned int u; } c; c.f = f;
  unsigned int u = c.u + 0x7fffu + ((c.u >> 16) & 1u);
  return (unsigned short)(u >> 16);
}

// ---------------- Kernel 1: x fp32 -> bf16 (32B load / 16B store per thread) ----
__global__ void convert_x_kernel(const float4* __restrict__ x, u16x8* __restrict__ out) {
  int idx = blockIdx.x * 256 + threadIdx.x;
  float4 v0 = x[2 * idx];
  float4 v1 = x[2 * idx + 1];
  u16x8 o;
  o[0] = f2bf(v0.x); o[1] = f2bf(v0.y); o[2] = f2bf(v0.z); o[3] = f2bf(v0.w);
  o[4] = f2bf(v1.x); o[5] = f2bf(v1.y); o[6] = f2bf(v1.z); o[7] = f2bf(v1.w);
  out[idx] = o;
}

// ---------------- Kernel 2: fold SRHT into A2 / B2t via FWHT (1024 thr) --------
__global__ __launch_bounds__(1024) void srht_fold_kernel(
    const float* __restrict__ A, const float* __restrict__ Bm,
    const float* __restrict__ in_signs, const float* __restrict__ out_signs,
    const int* __restrict__ in_perm, const int* __restrict__ out_perm,
    float* __restrict__ A2, float* __restrict__ B2t) {
  __shared__ float buf[DDIM];
  const int tid = threadIdx.x;
  const int b = blockIdx.x;
  if (b < RANK) {
    const int r = b;
    for (int j = tid; j < DDIM; j += 1024) {
      int p = in_perm[j];
      buf[j] = in_signs[p] * A[r * DDIM + p];
    }
  } else {
    const int r = b - RANK;
    for (int j = tid; j < DDIM; j += 1024) {
      int p = out_perm[j];
      buf[j] = out_signs[p] * Bm[p * RANK + r];
    }
  }
  __syncthreads();
  for (int h = 1; h < DDIM; h <<= 1) {
    for (int p = tid; p < DDIM / 2; p += 1024) {
      int j = p & (h - 1);
      int i0 = ((p - j) << 1) + j;
      int i1 = i0 + h;
      float a = buf[i0], c = buf[i1];
      buf[i0] = a + c;
      buf[i1] = a - c;
    }
    __syncthreads();
  }
  const float scale = (b < RANK) ? (1.0f / 64.0f) : (2.0f / 64.0f);  // 2/64 folds SCALE
  float* dst = (b < RANK) ? (A2 + b * DDIM) : (B2t + (b - RANK) * DDIM);
  for (int j = tid; j < DDIM; j += 1024) dst[j] = buf[j] * scale;
}

// ---------------- Kernel 3: Weff = bf16(W + B2*A2) ----------------
__global__ void weff_kernel(const float4* __restrict__ W, const float* __restrict__ A2,
                            const float* __restrict__ B2t, u16x8* __restrict__ Weff) {
  int idx = blockIdx.x * 256 + threadIdx.x;  // 8-float groups: 4096*512
  int o = idx >> 9;                          // output row
  int c8 = idx & 511;                        // 8-float group within row
  float4 w0 = W[2 * idx];
  float4 w1 = W[2 * idx + 1];
#pragma unroll
  for (int r = 0; r < RANK; ++r) {
    float s = B2t[r * DDIM + o];
    const float4* av = (const float4*)(A2 + r * DDIM) + 2 * c8;
    float4 a0 = av[0], a1 = av[1];
    w0.x += s * a0.x; w0.y += s * a0.y; w0.z += s * a0.z; w0.w += s * a0.w;
    w1.x += s * a1.x; w1.y += s * a1.y; w1.z += s * a1.z; w1.w += s * a1.w;
  }
  u16x8 u;
  u[0] = f2bf(w0.x); u[1] = f2bf(w0.y); u[2] = f2bf(w0.z); u[3] = f2bf(w0.w);
  u[4] = f2bf(w1.x); u[5] = f2bf(w1.y); u[6] = f2bf(w1.z); u[7] = f2bf(w1.w);
  Weff[idx] = u;
}

// ---------------- Kernel 4: C = A * B^T + bias ----------------
// R5: 8-phase 256x256 schedule (m201 template, plain HIP). Previous 2-barrier
// structure ceilinged at 911 TF (vmcnt(0) drain at every __syncthreads). Here:
// BK=64, 512 thr (8 waves = 2Mx4N, wave tile 128x64 as 4x2 of 32x32x16 MFMA),
// double-buffered 128 KiB LDS. Staging = 4 half-tile units/K-tile of
// 2 global_load_lds each; one unit issued per phase into a region freed by a
// previous phase barrier; s_waitcnt vmcnt(4) (never 0) only at phases 4/8.
// Steady-state issue: uA0/uA1(t+1)@P1/P2 -> buf1.A, uB0/uB1(t+2)@P3/P4 -> buf0.B,
// uA0/uA1(t+2)@P5/P6 -> buf0.A, uB0/uB1(t+3)@P7/P8 -> buf1.B.
// vmcnt(4)@P4 waits tile t+1 (leaves uB(t+2) in flight); vmcnt(4)@P8 waits t+2.
// Fragment addressing + swizzle byte-identical to R4 (verified, 0 bank conflicts).
__device__ __forceinline__ void async_copy16(const unsigned short* g, unsigned short* l) {
  __builtin_amdgcn_global_load_lds(
      (const __attribute__((address_space(1))) unsigned int*)g,
      (__attribute__((address_space(3))) unsigned int*)l, 16, 0, 0);
}

#define BARX() __builtin_amdgcn_s_barrier()
#define LGKM0() asm volatile("s_waitcnt lgkmcnt(0)" ::: "memory")
#define VMCNT(n) asm volatile("s_waitcnt vmcnt(" #n ")" ::: "memory")

__global__ __launch_bounds__(512, 2) void gemm_bt_kernel(
    const unsigned short* __restrict__ Ab,   // M x K bf16 (x)
    const unsigned short* __restrict__ Bb,   // N x K bf16 (Weff)
    const float* __restrict__ bias,
    float* __restrict__ C) {                 // M x N fp32
  constexpr int K = 4096, N = 4096;
  __shared__ unsigned short As[2][256 * 64];   // 2 x 32 KB
  __shared__ unsigned short Bs[2][256 * 64];   // 2 x 32 KB

  const int tid = threadIdx.x;
  const int pid = blockIdx.x;                // 512 blocks: 32 m x 16 n
  // bijective XCD swizzle (512 % 8 == 0), then GROUP_M=8 grouping:
  // each XCD works an 8x8 block panel -> per-K-step L2 set ~512 KB.
  const int swzp = (pid & 7) * 64 + (pid >> 3);
  const int gg = swzp >> 7;                  // / (8*16)
  const int ll = swzp & 127;
  const int mBase = (gg * 8 + (ll & 7)) * 256;
  const int nBase = (ll >> 3) * 256;

  // --- staging addressing: per unit (128 rows) = 2 rounds of 512 thr x 16B ---
  const int sr = tid >> 3;                               // row 0..63 within round
  const int swz_s = (sr & 7) ^ ((sr >> 3) & 3);
  const int sc = (tid & 7) ^ swz_s;                      // pre-swizzled global chunk
  const size_t aOff = (size_t)(mBase + sr) * K + sc * 8;
  const size_t bOff = (size_t)(nBase + sr) * K + sc * 8;

#define STAGE_A(buf, unit, tt)                                                        \
  do {                                                                                \
    async_copy16(Ab + aOff + (size_t)((unit) * 128) * K + (size_t)(tt) * 64,          \
                 &As[buf][((unit) * 128) * 64 + tid * 8]);                            \
    async_copy16(Ab + aOff + (size_t)((unit) * 128 + 64) * K + (size_t)(tt) * 64,     \
                 &As[buf][((unit) * 128 + 64) * 64 + tid * 8]);                       \
  } while (0)
#define STAGE_B(buf, unit, tt)                                                        \
  do {                                                                                \
    async_copy16(Bb + bOff + (size_t)((unit) * 128) * K + (size_t)(tt) * 64,          \
                 &Bs[buf][((unit) * 128) * 64 + tid * 8]);                            \
    async_copy16(Bb + bOff + (size_t)((unit) * 128 + 64) * K + (size_t)(tt) * 64,     \
                 &Bs[buf][((unit) * 128 + 64) * 64 + tid * 8]);                       \
  } while (0)

  // --- fragment addressing (32x32x16: m/n = lane&31, k = (lane>>5)*8 + j) ---
  const int lane = tid & 63;
  const int wid = tid >> 6;                // 0..7
  const int wm = wid >> 2;                 // 0..1 -> M half (128 rows)
  const int wn = wid & 3;                  // 0..3 -> N quarter (64 cols)
  const int lm = lane & 31;
  const int half = lane >> 5;
  const int swz_f = (lm & 7) ^ ((lm >> 3) & 3);

  int aoff[4][4], boff[2][4];
#pragma unroll
  for (int mt = 0; mt < 4; ++mt) {
    int r = wm * 128 + mt * 32 + lm;
#pragma unroll
    for (int ks = 0; ks < 4; ++ks) {
      int c = ks * 2 + half;
      aoff[mt][ks] = r * 64 + ((c ^ swz_f) * 8);
    }
  }
#pragma unroll
  for (int nt = 0; nt < 2; ++nt) {
    int r = wn * 64 + nt * 32 + lm;
#pragma unroll
    for (int ks = 0; ks < 4; ++ks) {
      int c = ks * 2 + half;
      boff[nt][ks] = r * 64 + ((c ^ swz_f) * 8);
    }
  }

  f32x16 acc[4][2];
#pragma unroll
  for (int mt = 0; mt < 4; ++mt)
#pragma unroll
    for (int nt = 0; nt < 2; ++nt)
#pragma unroll
      for (int i = 0; i < 16; ++i) acc[mt][nt][i] = 0.f;

  bf16x8 afr[2][4];   // current mh pair of A fragments
  bf16x8 bfr[2][4];   // both Nt fragments, live across a K-tile's 4 phases

#define READ_AF(buf, mh)                                                        \
  do {                                                                          \
    _Pragma("unroll") for (int qq = 0; qq < 2; ++qq)                            \
    _Pragma("unroll") for (int kk = 0; kk < 4; ++kk)                            \
        afr[qq][kk] = *(const bf16x8*)(&As[buf][aoff[(mh) * 2 + qq][kk]]);      \
  } while (0)
#define READ_BF(buf, nh)                                                        \
  do {                                                                          \
    _Pragma("unroll") for (int kk = 0; kk < 4; ++kk)                            \
        bfr[nh][kk] = *(const bf16x8*)(&Bs[buf][boff[nh][kk]]);                 \
  } while (0)
#define MFMA8(mh, nh)                                                           \
  do {                                                                          \
    __builtin_amdgcn_s_setprio(1);                                              \
    _Pragma("unroll") for (int kk = 0; kk < 4; ++kk)                            \
    _Pragma("unroll") for (int qq = 0; qq < 2; ++qq)                            \
        acc[(mh) * 2 + qq][nh] = __builtin_amdgcn_mfma_f32_32x32x16_bf16(       \
            afr[qq][kk], bfr[nh][kk], acc[(mh) * 2 + qq][nh], 0, 0, 0);         \
    __builtin_amdgcn_s_setprio(0);                                              \
  } while (0)

  // ---- prologue: tile 0 fully + B-halves of tile 1 ----
  STAGE_A(0, 0, 0); STAGE_A(0, 1, 0); STAGE_B(0, 0, 0); STAGE_B(0, 1, 0);
  STAGE_B(1, 0, 1); STAGE_B(1, 1, 1);
  VMCNT(4);           // tile 0 landed; uB(1) in flight
  BARX();

#pragma clang loop unroll(disable)
  for (int I = 0; I < 31; ++I) {
    const int t = 2 * I;
    // P1: compute (mh0,nh0) of buf0
    READ_AF(0, 0); READ_BF(0, 0);
    STAGE_A(1, 0, t + 1);            // buf1.A[0:128) freed at P7 of prev iter
    BARX(); LGKM0();
    MFMA8(0, 0);
    BARX();
    // P2: (mh0,nh1)
    READ_BF(0, 1);
    STAGE_A(1, 1, t + 1);
    BARX(); LGKM0();
    MFMA8(0, 1);
    BARX();
    // P3: (mh1,nh0)   buf0.B fully read after P2 -> restage for t+2
    READ_AF(0, 1);
    STAGE_B(0, 0, t + 2);
    BARX(); LGKM0();
    MFMA8(1, 0);
    BARX();
    // P4: (mh1,nh1); wait tile t+1 (leave uB(t+2) = 4 loads in flight)
    STAGE_B(0, 1, t + 2);
    BARX();
    MFMA8(1, 1);
    VMCNT(4);
    BARX();
    // P5: compute (mh0,nh0) of buf1; buf0.A freed after P3 -> restage for t+2
    READ_AF(1, 0); READ_BF(1, 0);
    STAGE_A(0, 0, t + 2);
    BARX(); LGKM0();
    MFMA8(0, 0);
    BARX();
    // P6
    READ_BF(1, 1);
    STAGE_A(0, 1, t + 2);
    BARX(); LGKM0();
    MFMA8(0, 1);
    BARX();
    // P7: buf1.B fully read after P6 -> restage for t+3
    READ_AF(1, 1);
    STAGE_B(1, 0, t + 3);
    BARX(); LGKM0();
    MFMA8(1, 0);
    BARX();
    // P8: wait tile t+2 (leave uB(t+3) = 4 loads in flight)
    STAGE_B(1, 1, t + 3);
    BARX();
    MFMA8(1, 1);
    VMCNT(4);
    BARX();
  }

  // ---- tail iteration: tiles 62 (buf0) and 63 (buf1); no t+2/t+3 staging ----
  {
    // P1
    READ_AF(0, 0); READ_BF(0, 0);
    STAGE_A(1, 0, 63);
    BARX(); LGKM0();
    MFMA8(0, 0);
    BARX();
    // P2
    READ_BF(0, 1);
    STAGE_A(1, 1, 63);
    BARX(); LGKM0();
    MFMA8(0, 1);
    BARX();
    // P3
    READ_AF(0, 1);
    BARX(); LGKM0();
    MFMA8(1, 0);
    BARX();
    // P4: drain everything; tile 63 complete
    BARX();
    MFMA8(1, 1);
    VMCNT(0);
    BARX();
    // P5
    READ_AF(1, 0); READ_BF(1, 0);
    BARX(); LGKM0();
    MFMA8(0, 0);
    BARX();
    // P6
    READ_BF(1, 1);
    BARX(); LGKM0();
    MFMA8(0, 1);
    BARX();
    // P7
    READ_AF(1, 1);
    BARX(); LGKM0();
    MFMA8(1, 0);
    BARX();
    // P8 (no trailing barrier needed; epilogue is regs+global only)
    MFMA8(1, 1);
  }

  // epilogue: 32x32 C/D layout col=lane&31, row=(reg&3)+8*(reg>>2)+4*(lane>>5)
#pragma unroll
  for (int nt = 0; nt < 2; ++nt) {
    const int col = nBase + wn * 64 + nt * 32 + lm;
    const float bc = bias[col];
#pragma unroll
    for (int mt = 0; mt < 4; ++mt) {
      const int row0 = mBase + wm * 128 + mt * 32 + 4 * half;
      float* cp = C + (size_t)row0 * N + col;
#pragma unroll
      for (int reg = 0; reg < 16; ++reg) {
        int row = (reg & 3) + 8 * (reg >> 2);
        cp[(size_t)row * N] = acc[mt][nt][reg] + bc;
      }
    }
  }
}

// ---------------- launch ----------------
extern "C" void kernel_launch(void* const* d_in, const int* in_sizes, int n_in,
                              void* d_out, int out_size, void* d_ws, size_t ws_size,
                              hipStream_t stream) {
  const float* x        = (const float*)d_in[0];
  const float* W        = (const float*)d_in[1];
  const float* b        = (const float*)d_in[2];
  const float* A        = (const float*)d_in[3];
  const float* Bm       = (const float*)d_in[4];
  const float* in_signs = (const float*)d_in[5];
  const float* out_signs= (const float*)d_in[6];
  const int*   in_perm  = (const int*)d_in[7];
  const int*   out_perm = (const int*)d_in[9];
  float* out = (float*)d_out;

  char* ws = (char*)d_ws;
  unsigned short* x_bf = (unsigned short*)ws;                       // 64 MiB
  unsigned short* weff = (unsigned short*)(ws + (size_t)67108864);  // 32 MiB
  float* A2  = (float*)(ws + (size_t)67108864 + (size_t)33554432);
  float* B2t = A2 + RANK * DDIM;

  convert_x_kernel<<<16384, 256, 0, stream>>>((const float4*)x, (u16x8*)x_bf);
  srht_fold_kernel<<<16, 1024, 0, stream>>>(A, Bm, in_signs, out_signs, in_perm, out_perm,
                                            A2, B2t);
  weff_kernel<<<8192, 256, 0, stream>>>((const float4*)W, A2, B2t, (u16x8*)weff);
  gemm_bt_kernel<<<512, 512, 0, stream>>>(x_bf, weff, b, out);
}